// Round 2
// baseline (1576.795 us; speedup 1.0000x reference)
//
#include <hip/hip_runtime.h>
#include <cstdint>
#include <cstddef>

typedef unsigned short u16;
typedef __attribute__((ext_vector_type(8))) short bf16x8s;
typedef __attribute__((ext_vector_type(4))) float f32x4;

__device__ __forceinline__ u16 f2bf(float f){
  union { float f; unsigned u; } v; v.f = f;
  unsigned r = v.u + 0x7FFFu + ((v.u >> 16) & 1u);
  return (u16)(r >> 16);
}
__device__ __forceinline__ float bf2f(u16 h){
  union { unsigned u; float f; } v; v.u = ((unsigned)h) << 16;
  return v.f;
}

// ---------------- fp32 -> bf16 convert ----------------
__global__ __launch_bounds__(256) void cvt_kernel(const float* __restrict__ in,
                                                  u16* __restrict__ out, int n){
  int i = blockIdx.x*256 + threadIdx.x;
  if (i < n) out[i] = f2bf(in[i]);
}

// ---------------- temb branch: tvec[b][col] = temb@Wt^T + bt + bqkv ----------------
__global__ __launch_bounds__(256) void temb_kernel(const float* __restrict__ temb,
                                                   const float* __restrict__ Wt,
                                                   const float* __restrict__ bt,
                                                   const float* __restrict__ bqkv,
                                                   float* __restrict__ tvec){
  int idx = blockIdx.x*256 + threadIdx.x;
  if (idx >= 16*3456) return;
  int b = idx / 3456, col = idx % 3456;
  const float* tp = temb + (size_t)b*1152;
  const float* wp = Wt + (size_t)col*1152;
  float s = 0.f;
  for (int k=0;k<1152;k++) s += tp[k]*wp[k];
  tvec[idx] = s + bt[col] + bqkv[col];
}

// ---------------- row RMSNorm (no affine), fp32 in -> bf16 out ----------------
__global__ __launch_bounds__(256) void rms_kernel(const float* __restrict__ in,
                                                  u16* __restrict__ out, int C){
  int row = blockIdx.x;
  const float* p = in + (size_t)row*C;
  float ss = 0.f;
  for (int c = threadIdx.x; c < C; c += 256){ float v = p[c]; ss += v*v; }
  #pragma unroll
  for (int d=1; d<64; d<<=1) ss += __shfl_xor(ss, d);
  __shared__ float wsum[4];
  if ((threadIdx.x & 63) == 0) wsum[threadIdx.x>>6] = ss;
  __syncthreads();
  float tot = wsum[0]+wsum[1]+wsum[2]+wsum[3];
  float r = rsqrtf(tot/(float)C + 1e-6f);
  u16* o = out + (size_t)row*C;
  for (int c = threadIdx.x; c < C; c += 256) o[c] = f2bf(p[c]*r);
}

// ---------------- GEMM: Y[M][N] = A[M][K](bf16) @ B[N][K]^T(bf16), fused epilogues ----------------
// MODE 0: QKV -> +tvec, scatter: q->outv(bf16 [bh][n][72]), k->out2, v->out3 ([bh][72][1024])
// MODE 1: PROJ -> + bias[col] + fextra(x)[row][col],    out f32
// MODE 2: GATE -> + bias[col],                          out bf16 (raw g)
// MODE 3: UP   -> u=v+bias; h=silu(g)*u,                out bf16 (over g)
// MODE 4: DOWN -> + bias[col] + fextra[row][col],       out f32 (fextra may be == outv)
template<int MODE>
__global__ __launch_bounds__(256) void gemm_kernel(
    const u16* __restrict__ A, const u16* __restrict__ B,
    int M, int N, int K,
    const float* __restrict__ bias, const float* __restrict__ fextra,
    const u16* __restrict__ gextra, void* __restrict__ outv,
    u16* __restrict__ out2, u16* __restrict__ out3)
{
  __shared__ __align__(16) u16 As[128*32];
  __shared__ __align__(16) u16 Bs[128*32];
  const int lane = threadIdx.x & 63;
  const int wv   = threadIdx.x >> 6;
  const int wr   = wv >> 1, wc = wv & 1;
  const long m0 = (long)blockIdx.y * 128;
  const long n0 = (long)blockIdx.x * 128;

  f32x4 acc[4][4];
  #pragma unroll
  for (int i=0;i<4;i++)
    #pragma unroll
    for (int j=0;j<4;j++) acc[i][j] = (f32x4){0.f,0.f,0.f,0.f};

  const int srow = lane >> 2;        // 0..15 rows within a 16-row shot
  const int scol = (lane & 3) * 8;   // element offset within BK=32

  for (int kt = 0; kt < K; kt += 32) {
    #pragma unroll
    for (int c=0;c<2;c++){
      int s = wv*2 + c;              // shot 0..7, 16 rows each
      const u16* ga = A + (size_t)(m0 + s*16 + srow)*K + kt + scol;
      const u16* gb = B + (size_t)(n0 + s*16 + srow)*K + kt + scol;
      __builtin_amdgcn_global_load_lds((const __attribute__((address_space(1))) void*)ga,
          (__attribute__((address_space(3))) void*)(As + s*512), 16, 0, 0);
      __builtin_amdgcn_global_load_lds((const __attribute__((address_space(1))) void*)gb,
          (__attribute__((address_space(3))) void*)(Bs + s*512), 16, 0, 0);
    }
    __syncthreads();
    const int kb = (lane>>4)*8;
    bf16x8s af[4], bfr[4];
    #pragma unroll
    for (int i=0;i<4;i++)
      af[i] = *(const bf16x8s*)(As + (wr*64 + i*16 + (lane&15))*32 + kb);
    #pragma unroll
    for (int j=0;j<4;j++)
      bfr[j] = *(const bf16x8s*)(Bs + (wc*64 + j*16 + (lane&15))*32 + kb);
    #pragma unroll
    for (int i=0;i<4;i++)
      #pragma unroll
      for (int j=0;j<4;j++)
        acc[i][j] = __builtin_amdgcn_mfma_f32_16x16x32_bf16(af[i], bfr[j], acc[i][j], 0,0,0);
    __syncthreads();
  }

  const int lr = (lane>>4)*4, lc = lane&15;
  #pragma unroll
  for (int i=0;i<4;i++){
    #pragma unroll
    for (int j=0;j<4;j++){
      long colg = n0 + wc*64 + j*16 + lc;
      int which=0, hh=0, dd=0;
      if (MODE==0){
        int cg = (int)colg;
        which = cg / 1152;
        int rem = cg - which*1152;
        hh = rem / 72;
        dd = rem - hh*72;
      }
      #pragma unroll
      for (int r=0;r<4;r++){
        long rowg = m0 + wr*64 + i*16 + lr + r;
        float v = acc[i][j][r];
        size_t oi = (size_t)rowg*N + colg;
        if (MODE==0){
          v += fextra[(size_t)(rowg>>10)*3456 + colg];
          int b = (int)(rowg>>10), n = (int)(rowg&1023);
          size_t bh = (size_t)(b*16 + hh);
          u16 val = f2bf(v);
          if (which==0)      ((u16*)outv)[(bh*1024+n)*72 + dd] = val;
          else if (which==1) out2[(bh*1024+n)*72 + dd] = val;
          else               out3[(bh*72+dd)*1024 + n] = val;
        } else if (MODE==1){
          v += bias[colg] + fextra[oi];
          ((float*)outv)[oi] = v;
        } else if (MODE==2){
          v += bias[colg];
          ((u16*)outv)[oi] = f2bf(v);
        } else if (MODE==3){
          float u = v + bias[colg];
          float g = bf2f(gextra[oi]);
          float h = (g / (1.f + __expf(-g))) * u;
          ((u16*)outv)[oi] = f2bf(h);
        } else {
          v += bias[colg] + fextra[oi];
          ((float*)outv)[oi] = v;
        }
      }
    }
  }
}

// ---------------- per-(b,h,n): q/k RMS(+weight) + axial RoPE, IN PLACE ----------------
// Q/K: [B*H*N][72] bf16.
__global__ __launch_bounds__(256) void qkrope_kernel(
    u16* __restrict__ Q, u16* __restrict__ K,
    const float* __restrict__ qn_w, const float* __restrict__ kn_w,
    const float* __restrict__ cos_y, const float* __restrict__ sin_y,
    const float* __restrict__ cos_x, const float* __restrict__ sin_x)
{
  const int gw   = blockIdx.x*4 + (threadIdx.x>>6);   // row over B*H*N = 262144
  const int lane = threadIdx.x & 63;
  const int n = gw & 1023;
  const int d0 = lane*2;
  const bool act = d0 < 72;

  u16* qp = Q + (size_t)gw*72;
  u16* kp = K + (size_t)gw*72;
  float q0=0,q1=0,k0=0,k1=0,wq0=0,wq1=0,wk0=0,wk1=0;
  if (act){
    q0 = bf2f(qp[d0]); q1 = bf2f(qp[d0+1]);
    k0 = bf2f(kp[d0]); k1 = bf2f(kp[d0+1]);
    wq0 = qn_w[d0]; wq1 = qn_w[d0+1];
    wk0 = kn_w[d0]; wk1 = kn_w[d0+1];
  }
  float ssq = q0*q0 + q1*q1;
  float ssk = k0*k0 + k1*k1;
  #pragma unroll
  for (int d=1; d<64; d<<=1){ ssq += __shfl_xor(ssq,d); ssk += __shfl_xor(ssk,d); }
  const float rq = rsqrtf(ssq*(1.f/72.f) + 1e-6f);
  const float rk = rsqrtf(ssk*(1.f/72.f) + 1e-6f);
  float qn0 = q0*rq*wq0, qn1 = q1*rq*wq1;
  float kn0 = k0*rk*wk0, kn1 = k1*rk*wk1;

  int dh = d0 % 36;
  const bool first = (dh < 18);
  int partner = first ? lane+9 : lane-9;
  if (!act) partner = lane;
  float pq0 = __shfl(qn0, partner), pq1 = __shfl(qn1, partner);
  float pk0 = __shfl(kn0, partner), pk1 = __shfl(kn1, partner);
  if (act){
    const float* cp = (d0 < 36) ? cos_y : cos_x;
    const float* sp = (d0 < 36) ? sin_y : sin_x;
    float c0 = cp[n*36+dh], c1 = cp[n*36+dh+1];
    float s0 = sp[n*36+dh], s1 = sp[n*36+dh+1];
    float sgn = first ? -1.f : 1.f;
    float qo0 = qn0*c0 + sgn*pq0*s0, qo1 = qn1*c1 + sgn*pq1*s1;
    float ko0 = kn0*c0 + sgn*pk0*s0, ko1 = kn1*c1 + sgn*pk1*s1;
    *(unsigned*)(qp + d0) = (unsigned)f2bf(qo0) | ((unsigned)f2bf(qo1)<<16);
    *(unsigned*)(kp + d0) = (unsigned)f2bf(ko0) | ((unsigned)f2bf(ko1)<<16);
  }
}

// ---------------- flash attention: block = (b,h) x 64 q-rows, KVB=64 ----------------
// Q/K: [bh][1024][72] bf16 (stride 72); Vt: [bh][72][1024]; O: [b][n][1152] at head offset.
__global__ __launch_bounds__(256) void attn_kernel(
    const u16* __restrict__ Q, const u16* __restrict__ K,
    const u16* __restrict__ Vt, u16* __restrict__ O)
{
  const int bh = blockIdx.x;       // 0..255
  const int q0 = blockIdx.y * 64;  // 16 q tiles
  const int lane = threadIdx.x & 63;
  const int wv   = threadIdx.x >> 6;
  const int b = bh >> 4, h = bh & 15;

  __shared__ __align__(16) u16 Plds[4][16][64];
  const bf16x8s zf = {0,0,0,0,0,0,0,0};

  const u16* Qp = Q + ((size_t)bh*1024 + q0 + wv*16)*72;
  const u16* Kp = K + (size_t)bh*1024*72;
  const u16* Vp = Vt + (size_t)bh*72*1024;

  bf16x8s qf0, qf1, qf2;
  {
    const u16* qrow = Qp + (size_t)(lane&15)*72 + (lane>>4)*8;
    qf0 = *(const bf16x8s*)(qrow);
    qf1 = *(const bf16x8s*)(qrow + 32);
    qf2 = zf;
    if ((lane>>4)==0) qf2 = *(const bf16x8s*)(Qp + (size_t)(lane&15)*72 + 64);
  }

  float m_run[4], l_run[4];
  f32x4 oacc[5];
  #pragma unroll
  for (int r=0;r<4;r++){ m_run[r] = -1e30f; l_run[r] = 0.f; }
  #pragma unroll
  for (int c=0;c<5;c++) oacc[c] = (f32x4){0.f,0.f,0.f,0.f};

  const float scale = 0.11785113019775793f;  // 1/sqrt(72)

  for (int kv0 = 0; kv0 < 1024; kv0 += 64) {
    f32x4 sc[4];
    #pragma unroll
    for (int nf=0; nf<4; nf++){
      sc[nf] = (f32x4){0.f,0.f,0.f,0.f};
      const u16* krow = Kp + (size_t)(kv0 + nf*16 + (lane&15))*72;
      bf16x8s kf0 = *(const bf16x8s*)(krow + (lane>>4)*8);
      bf16x8s kf1 = *(const bf16x8s*)(krow + 32 + (lane>>4)*8);
      bf16x8s kf2 = zf;
      if ((lane>>4)==0) kf2 = *(const bf16x8s*)(krow + 64);
      sc[nf] = __builtin_amdgcn_mfma_f32_16x16x32_bf16(qf0, kf0, sc[nf],0,0,0);
      sc[nf] = __builtin_amdgcn_mfma_f32_16x16x32_bf16(qf1, kf1, sc[nf],0,0,0);
      sc[nf] = __builtin_amdgcn_mfma_f32_16x16x32_bf16(qf2, kf2, sc[nf],0,0,0);
    }
    float tm[4];
    #pragma unroll
    for (int r=0;r<4;r++)
      tm[r] = fmaxf(fmaxf(sc[0][r],sc[1][r]), fmaxf(sc[2][r],sc[3][r])) * scale;
    #pragma unroll
    for (int d=1; d<16; d<<=1)
      #pragma unroll
      for (int r=0;r<4;r++) tm[r] = fmaxf(tm[r], __shfl_xor(tm[r], d));
    float corr[4], ts[4];
    #pragma unroll
    for (int r=0;r<4;r++){
      float mn = fmaxf(m_run[r], tm[r]);
      corr[r] = __expf(m_run[r] - mn);
      m_run[r] = mn;
      ts[r] = 0.f;
    }
    float p[4][4];
    #pragma unroll
    for (int nf=0;nf<4;nf++)
      #pragma unroll
      for (int r=0;r<4;r++){
        float pv = __expf(sc[nf][r]*scale - m_run[r]);
        p[nf][r] = pv; ts[r] += pv;
      }
    #pragma unroll
    for (int d=1; d<16; d<<=1)
      #pragma unroll
      for (int r=0;r<4;r++) ts[r] += __shfl_xor(ts[r], d);
    #pragma unroll
    for (int r=0;r<4;r++) l_run[r] = l_run[r]*corr[r] + ts[r];
    #pragma unroll
    for (int c=0;c<5;c++)
      #pragma unroll
      for (int r=0;r<4;r++) oacc[c][r] *= corr[r];

    // P -> LDS (D-layout to A-layout transpose), per-wave region
    #pragma unroll
    for (int nf=0;nf<4;nf++)
      #pragma unroll
      for (int r=0;r<4;r++)
        Plds[wv][4*(lane>>4)+r][nf*16+(lane&15)] = f2bf(p[nf][r]);
    asm volatile("" ::: "memory");
    bf16x8s pa0 = *(const bf16x8s*)&Plds[wv][lane&15][(lane>>4)*8];
    bf16x8s pa1 = *(const bf16x8s*)&Plds[wv][lane&15][32 + (lane>>4)*8];

    #pragma unroll
    for (int c=0;c<5;c++){
      bf16x8s vf0, vf1;
      if (c < 4){
        const u16* vrow = Vp + (size_t)(c*16 + (lane&15))*1024 + kv0 + (lane>>4)*8;
        vf0 = *(const bf16x8s*)(vrow);
        vf1 = *(const bf16x8s*)(vrow + 32);
      } else {
        vf0 = zf; vf1 = zf;
        if ((lane&15) < 8){
          const u16* vrow = Vp + (size_t)(64 + (lane&15))*1024 + kv0 + (lane>>4)*8;
          vf0 = *(const bf16x8s*)(vrow);
          vf1 = *(const bf16x8s*)(vrow + 32);
        }
      }
      oacc[c] = __builtin_amdgcn_mfma_f32_16x16x32_bf16(pa0, vf0, oacc[c],0,0,0);
      oacc[c] = __builtin_amdgcn_mfma_f32_16x16x32_bf16(pa1, vf1, oacc[c],0,0,0);
    }
  }

  size_t obase = ((size_t)b*1024)*1152 + (size_t)h*72;
  #pragma unroll
  for (int c=0;c<5;c++){
    int d = c*16 + (lane&15);
    if (d < 72){
      #pragma unroll
      for (int r=0;r<4;r++){
        int n = q0 + wv*16 + 4*(lane>>4) + r;
        O[obase + (size_t)n*1152 + d] = f2bf(oacc[c][r] / l_run[r]);
      }
    }
  }
}

extern "C" void kernel_launch(void* const* d_in, const int* in_sizes, int n_in,
                              void* d_out, int out_size, void* d_ws, size_t ws_size,
                              hipStream_t stream) {
  const float* x    = (const float*)d_in[0];
  const float* temb = (const float*)d_in[1];
  const float* cos_y= (const float*)d_in[2];
  const float* sin_y= (const float*)d_in[3];
  const float* cos_x= (const float*)d_in[4];
  const float* sin_x= (const float*)d_in[5];
  const float* Wqkv = (const float*)d_in[6];
  const float* bqkv = (const float*)d_in[7];
  const float* Wt   = (const float*)d_in[8];
  const float* bt   = (const float*)d_in[9];
  const float* Wp   = (const float*)d_in[10];
  const float* bp   = (const float*)d_in[11];
  const float* qn_w = (const float*)d_in[12];
  const float* kn_w = (const float*)d_in[13];
  const float* Wg   = (const float*)d_in[14];
  const float* bg   = (const float*)d_in[15];
  const float* Wu   = (const float*)d_in[16];
  const float* bu   = (const float*)d_in[17];
  const float* Wd   = (const float*)d_in[18];
  const float* bd   = (const float*)d_in[19];

  char* ws = (char*)d_ws;
  size_t off = 0;
  auto alloc = [&](size_t bytes)->void*{
    off = (off + 255) & ~(size_t)255;
    void* p = ws + off; off += bytes; return p;
  };

  u16*   wbuf  = (u16*)alloc((size_t)3456*1152*2);          // shared bf16 weight buffer (max size)
  float* tvec  = (float*)alloc((size_t)16*3456*4);
  u16*   xn_bf = (u16*)alloc((size_t)16384*1152*2);         // norm1 out -> o (attn out) -> xn2
  u16*   qt    = (u16*)alloc((size_t)262144*72*2);          // gbuf starts here later
  u16*   kt    = (u16*)alloc((size_t)262144*72*2);
  u16*   vt    = (u16*)alloc((size_t)256*72*1024*2);
  if (off > ws_size) return;   // diagnostic guard: clean fail instead of OOB crash

  u16*   o_bf   = xn_bf;
  u16*   xn2_bf = xn_bf;
  u16*   gbuf   = qt;          // 100.7 MB <= qt+kt+vt region (113.2 MB)
  float* x1     = (float*)d_out;

  // norm1 + temb branch
  rms_kernel<<<16384,256,0,stream>>>(x, xn_bf, 1152);
  temb_kernel<<<(16*3456+255)/256,256,0,stream>>>(temb, Wt, bt, bqkv, tvec);

  // QKV GEMM (scatter epilogue -> qt/kt/vt)
  cvt_kernel<<<(3456*1152+255)/256,256,0,stream>>>(Wqkv, wbuf, 3456*1152);
  gemm_kernel<0><<<dim3(3456/128,16384/128),256,0,stream>>>(
      xn_bf, wbuf, 16384, 3456, 1152, nullptr, tvec, nullptr, qt, kt, vt);

  // q/k RMS + RoPE in place
  qkrope_kernel<<<65536,256,0,stream>>>(qt, kt, qn_w, kn_w, cos_y, sin_y, cos_x, sin_x);

  // attention -> o_bf
  attn_kernel<<<dim3(256,16),256,0,stream>>>(qt, kt, vt, o_bf);

  // proj + residual -> x1 (= d_out, fp32)
  cvt_kernel<<<(1152*1152+255)/256,256,0,stream>>>(Wp, wbuf, 1152*1152);
  gemm_kernel<1><<<dim3(1152/128,16384/128),256,0,stream>>>(
      o_bf, wbuf, 16384, 1152, 1152, bp, x, nullptr, x1, nullptr, nullptr);

  // norm2
  rms_kernel<<<16384,256,0,stream>>>(x1, xn2_bf, 1152);

  // gate
  cvt_kernel<<<(3072*1152+255)/256,256,0,stream>>>(Wg, wbuf, 3072*1152);
  gemm_kernel<2><<<dim3(3072/128,16384/128),256,0,stream>>>(
      xn2_bf, wbuf, 16384, 3072, 1152, bg, nullptr, nullptr, gbuf, nullptr, nullptr);

  // up (+ silu(g)*u fused)
  cvt_kernel<<<(3072*1152+255)/256,256,0,stream>>>(Wu, wbuf, 3072*1152);
  gemm_kernel<3><<<dim3(3072/128,16384/128),256,0,stream>>>(
      xn2_bf, wbuf, 16384, 3072, 1152, bu, nullptr, gbuf, gbuf, nullptr, nullptr);

  // down + residual -> d_out (reads x1 == d_out element-wise, race-free)
  cvt_kernel<<<(1152*3072+255)/256,256,0,stream>>>(Wd, wbuf, 1152*3072);
  gemm_kernel<4><<<dim3(1152/128,16384/128),256,0,stream>>>(
      gbuf, wbuf, 16384, 1152, 3072, bd, x1, nullptr, (float*)d_out, nullptr, nullptr);
}